// Round 9
// baseline (1852.368 us; speedup 1.0000x reference)
//
#include <hip/hip_runtime.h>

// LightGCN conv via 3-level exact counting sort, no refine, no output atomics:
//   per side: count1 -> exscan -> p1 (1024-row L1 buckets, long write runs)
//             count2 -> exscan -> p2 (4-row sub-buckets, 512B write runs)
//             acc (one block per 4-row sub-bucket, LDS-staged segment,
//                  4 waves filter their own row, bf16 gather tables).
// R9: R8's partition had 3.7x write amplification (14-pair runs fragmented
// across 8 XCD L2 write frontiers) at 24% occupancy. Long runs fix it.

constexpr int DIM    = 64;
constexpr int L1BITS = 10;
constexpr int L1SZ   = 1 << L1BITS;       // rows per L1 bucket
constexpr int SUBCNT = 256;               // 4-row sub-buckets per L1 bucket
constexpr int SHIFT  = 17;                // bits for neighbor id
constexpr unsigned NMASK = (1u << SHIFT) - 1;
constexpr int C1     = 4096;              // edges per p1 block
constexpr int C2     = 16384;             // pairs per count2/p2 block
constexpr int K1MAX  = 128;

// ---------------- fallback (round-1) atomic kernel ----------------
__global__ void lightgcn_scatter_atomic(const float* __restrict__ user_emb,
                                        const float* __restrict__ item_emb,
                                        const int* __restrict__ rows,
                                        const int* __restrict__ cols,
                                        const float* __restrict__ vals,
                                        float* __restrict__ user_out,
                                        float* __restrict__ item_out,
                                        int nnz) {
    const int lane   = threadIdx.x & 63;
    const int wave   = (blockIdx.x * blockDim.x + threadIdx.x) >> 6;
    const int nwaves = (gridDim.x * blockDim.x) >> 6;
    for (int e = wave; e < nnz; e += nwaves) {
        const int r = rows[e];
        const int c = cols[e];
        const float v = vals[e];
        atomicAdd(&user_out[(size_t)r * DIM + lane], v * item_emb[(size_t)c * DIM + lane]);
        atomicAdd(&item_out[(size_t)c * DIM + lane], v * user_emb[(size_t)r * DIM + lane]);
    }
}

// ---------------- bf16 table conversion (RNE) ----------------
__global__ void to_bf16(const float* __restrict__ a, int n, ushort* __restrict__ o) {
    int i = blockIdx.x * blockDim.x + threadIdx.x;
    const int s = gridDim.x * blockDim.x;
    for (; i < n; i += s) {
        const unsigned u = __float_as_uint(a[i]);
        o[i] = (ushort)((u + 0x7FFFu + ((u >> 16) & 1u)) >> 16);
    }
}

// ---------------- count1: L1-bucket histogram ----------------
__global__ __launch_bounds__(256)
void count1_kernel(const int* __restrict__ dest, int nnz, int K1,
                   int* __restrict__ counts1) {
    __shared__ int h[K1MAX * 4];
    const int tid = threadIdx.x;
    for (int t = tid; t < K1 * 4; t += 256) h[t] = 0;
    __syncthreads();
    const int rr = tid & 3;
    int i = blockIdx.x * 256 + tid;
    const int stride = gridDim.x * 256;
    for (; i < nnz; i += stride)
        atomicAdd(&h[((dest[i] >> L1BITS) << 2) | rr], 1);
    __syncthreads();
    for (int b = tid; b < K1; b += 256) {
        const int c = h[b*4] + h[b*4+1] + h[b*4+2] + h[b*4+3];
        if (c) atomicAdd(&counts1[b], c);
    }
}

// ---------------- single-block exclusive scan (n up to ~26K) ----------------
__global__ __launch_bounds__(1024)
void exscan_block(const int* __restrict__ src, int n,
                  int* __restrict__ base, int* __restrict__ cursor) {
    __shared__ int s[1024];
    const int tid = threadIdx.x;
    const int len = (n + 1023) >> 10;
    const int lo = min(tid * len, n);
    const int hi = min(lo + len, n);
    int sum = 0;
    for (int i = lo; i < hi; ++i) sum += src[i];
    s[tid] = sum;
    __syncthreads();
    for (int off = 1; off < 1024; off <<= 1) {
        const int t = (tid >= off) ? s[tid - off] : 0;
        __syncthreads();
        s[tid] += t;
        __syncthreads();
    }
    int run = tid ? s[tid - 1] : 0;
    for (int i = lo; i < hi; ++i) {
        const int c = src[i];
        base[i] = run; cursor[i] = run;
        run += c;
    }
}

// ---------------- p1: edges -> L1-bucket-grouped pairs ----------------
__global__ __launch_bounds__(256)
void p1_kernel(const int* __restrict__ dest, const int* __restrict__ nbr,
               const float* __restrict__ vals, int nnz, int K1,
               int* __restrict__ cursor1, uint2* __restrict__ pairs1) {
    __shared__ int h[K1MAX * 4];
    __shared__ int gd[K1MAX];
    __shared__ int lc[K1MAX];
    const int tid = threadIdx.x;
    const int e0 = blockIdx.x * C1;
    const int e1 = min(e0 + C1, nnz);
    for (int t = tid; t < K1 * 4; t += 256) h[t] = 0;
    for (int t = tid; t < K1; t += 256) lc[t] = 0;
    __syncthreads();
    const int rr = tid & 3;
    for (int e = e0 + tid; e < e1; e += 256)
        atomicAdd(&h[((dest[e] >> L1BITS) << 2) | rr], 1);
    __syncthreads();
    for (int b = tid; b < K1; b += 256) {
        const int c = h[b*4] + h[b*4+1] + h[b*4+2] + h[b*4+3];
        gd[b] = c ? atomicAdd(&cursor1[b], c) : 0;
    }
    __syncthreads();
    for (int e = e0 + tid; e < e1; e += 256) {
        const int d = dest[e];
        const int b = d >> L1BITS;
        const int slot = gd[b] + atomicAdd(&lc[b], 1);
        pairs1[slot] = make_uint2(((unsigned)(d & (L1SZ - 1)) << SHIFT) | (unsigned)nbr[e],
                                  __float_as_uint(vals[e]));
    }
}

// ---------------- count2: sub-bucket histogram within L1 buckets -------------
__global__ __launch_bounds__(512)
void count2_kernel(const uint2* __restrict__ pairs1,
                   const int* __restrict__ bases1, const int* __restrict__ counts1,
                   int CPB, int* __restrict__ counts2) {
    const int B = blockIdx.x / CPB;
    const int j = blockIdx.x % CPB;
    const int bstart = bases1[B];
    const int s0 = bstart + j * C2;
    const int s1 = min(s0 + C2, bstart + counts1[B]);
    if (s0 >= s1) return;   // uniform across block
    __shared__ int h[SUBCNT * 4];
    const int tid = threadIdx.x;
    for (int t = tid; t < SUBCNT * 4; t += 512) h[t] = 0;
    __syncthreads();
    const int rr = tid & 3;
    for (int i = s0 + tid; i < s1; i += 512) {
        const unsigned m = pairs1[i].x;
        atomicAdd(&h[((((int)(m >> (SHIFT + 2))) & (SUBCNT - 1)) << 2) | rr], 1);
    }
    __syncthreads();
    for (int s = tid; s < SUBCNT; s += 512) {
        const int c = h[s*4] + h[s*4+1] + h[s*4+2] + h[s*4+3];
        if (c) atomicAdd(&counts2[B * SUBCNT + s], c);
    }
}

// ---------------- p2: L1-bucket pairs -> 4-row-sub-bucket order --------------
__global__ __launch_bounds__(512)
void p2_kernel(const uint2* __restrict__ pairs1,
               const int* __restrict__ bases1, const int* __restrict__ counts1,
               int CPB, int* __restrict__ cursor2, uint2* __restrict__ pairs2) {
    const int B = blockIdx.x / CPB;
    const int j = blockIdx.x % CPB;
    const int bstart = bases1[B];
    const int s0 = bstart + j * C2;
    const int s1 = min(s0 + C2, bstart + counts1[B]);
    if (s0 >= s1) return;   // uniform across block
    __shared__ int h[SUBCNT * 4];
    __shared__ int gd[SUBCNT];
    __shared__ int lc[SUBCNT];
    const int tid = threadIdx.x;
    for (int t = tid; t < SUBCNT * 4; t += 512) h[t] = 0;
    for (int t = tid; t < SUBCNT; t += 512) lc[t] = 0;
    __syncthreads();
    const int rr = tid & 3;
    for (int i = s0 + tid; i < s1; i += 512) {
        const unsigned m = pairs1[i].x;
        atomicAdd(&h[((((int)(m >> (SHIFT + 2))) & (SUBCNT - 1)) << 2) | rr], 1);
    }
    __syncthreads();
    for (int s = tid; s < SUBCNT; s += 512) {
        const int c = h[s*4] + h[s*4+1] + h[s*4+2] + h[s*4+3];
        gd[s] = c ? atomicAdd(&cursor2[B * SUBCNT + s], c) : 0;
    }
    __syncthreads();
    for (int i = s0 + tid; i < s1; i += 512) {
        const uint2 p = pairs1[i];
        const int s = ((int)(p.x >> (SHIFT + 2))) & (SUBCNT - 1);
        const int slot = gd[s] + atomicAdd(&lc[s], 1);
        pairs2[slot] = p;
    }
}

// ---------------- acc: one block per 4-row sub-bucket ----------------
// 4 waves = 4 rows; segment tiled through LDS (coalesced global reads);
// each wave filters pairs for its row (dlow & 3) and gathers bf16 rows.
constexpr int SEGT = 1024;   // pairs per LDS tile (8 KB)

__global__ __launch_bounds__(256)
void acc_kernel(const ushort* __restrict__ tbl,
                const uint2* __restrict__ pairs2,
                const int* __restrict__ bases2, const int* __restrict__ counts2,
                int nrows, float* __restrict__ out) {
    __shared__ uint2 seg[SEGT];
    const int tid  = threadIdx.x;
    const int lane = tid & 63;
    const int rbase = blockIdx.x * 4;
    const int r = rbase + (tid >> 6);
    const int k2 = ((rbase >> L1BITS) << 8) | ((rbase >> 2) & (SUBCNT - 1));
    const int st = bases2[k2];
    const int en = st + counts2[k2];
    const unsigned want = (unsigned)(r & 3);
    float acc = 0.f;

    for (int tile = st; tile < en; tile += SEGT) {
        const int cnt = min(SEGT, en - tile);
        __syncthreads();
        for (int i = tid; i < cnt; i += 256) seg[i] = pairs2[tile + i];
        __syncthreads();
        int i = 0;
        for (; i + 4 <= cnt; i += 4) {
            const uint2 p0 = seg[i + 0];
            const uint2 p1 = seg[i + 1];
            const uint2 p2 = seg[i + 2];
            const uint2 p3 = seg[i + 3];
            if (((p0.x >> SHIFT) & 3u) == want)
                acc = fmaf(__uint_as_float(p0.y),
                           __uint_as_float((unsigned)tbl[(size_t)(p0.x & NMASK) * DIM + lane] << 16), acc);
            if (((p1.x >> SHIFT) & 3u) == want)
                acc = fmaf(__uint_as_float(p1.y),
                           __uint_as_float((unsigned)tbl[(size_t)(p1.x & NMASK) * DIM + lane] << 16), acc);
            if (((p2.x >> SHIFT) & 3u) == want)
                acc = fmaf(__uint_as_float(p2.y),
                           __uint_as_float((unsigned)tbl[(size_t)(p2.x & NMASK) * DIM + lane] << 16), acc);
            if (((p3.x >> SHIFT) & 3u) == want)
                acc = fmaf(__uint_as_float(p3.y),
                           __uint_as_float((unsigned)tbl[(size_t)(p3.x & NMASK) * DIM + lane] << 16), acc);
        }
        for (; i < cnt; ++i) {
            const uint2 p = seg[i];
            if (((p.x >> SHIFT) & 3u) == want)
                acc = fmaf(__uint_as_float(p.y),
                           __uint_as_float((unsigned)tbl[(size_t)(p.x & NMASK) * DIM + lane] << 16), acc);
        }
    }
    if (r < nrows) out[(size_t)r * DIM + lane] = acc;
}

extern "C" void kernel_launch(void* const* d_in, const int* in_sizes, int n_in,
                              void* d_out, int out_size, void* d_ws, size_t ws_size,
                              hipStream_t stream) {
    const float* user_emb = (const float*)d_in[0];
    const float* item_emb = (const float*)d_in[1];
    const int*   rows     = (const int*)d_in[2];
    const int*   cols     = (const int*)d_in[3];
    const float* vals     = (const float*)d_in[4];

    const int nnz     = in_sizes[2];
    const int n_users = in_sizes[0] / DIM;
    const int n_items = in_sizes[1] / DIM;

    float* user_out = (float*)d_out;
    float* item_out = (float*)d_out + (size_t)in_sizes[0];

    // ---- workspace layout (ints, then byte-aligned regions) ----
    const size_t K2MAX = (size_t)K1MAX * SUBCNT;   // 32768
    size_t oi = 0;
    const size_t counts1_o = oi; oi += K1MAX;
    const size_t counts2_o = oi; oi += K2MAX;      // adjacent to counts1: one memset
    const size_t bases1_o  = oi; oi += K1MAX;
    const size_t cursor1_o = oi; oi += K1MAX;
    const size_t bases2_o  = oi; oi += K2MAX;
    const size_t cursor2_o = oi; oi += K2MAX;
    const size_t meta_bytes = oi * sizeof(int);
    const size_t tbl_off    = (meta_bytes + 255) & ~(size_t)255;
    const size_t tblu_bytes = (size_t)n_users * DIM * sizeof(ushort);
    const size_t tbli_bytes = (size_t)n_items * DIM * sizeof(ushort);
    const size_t pairs1_off = (tbl_off + tblu_bytes + tbli_bytes + 255) & ~(size_t)255;
    const size_t pairs_bytes = (size_t)nnz * sizeof(uint2);
    const size_t pairs2_off = pairs1_off + ((pairs_bytes + 255) & ~(size_t)255);
    const size_t need = pairs2_off + pairs_bytes;

    if (n_users > (1 << SHIFT) || n_items > (1 << SHIFT) ||
        n_users > K1MAX * L1SZ || n_items > K1MAX * L1SZ || ws_size < need) {
        hipMemsetAsync(d_out, 0, (size_t)out_size * sizeof(float), stream);
        lightgcn_scatter_atomic<<<2048, 256, 0, stream>>>(user_emb, item_emb, rows,
                                                          cols, vals, user_out,
                                                          item_out, nnz);
        return;
    }

    int* wsi      = (int*)d_ws;
    int* counts1  = wsi + counts1_o;
    int* counts2  = wsi + counts2_o;
    int* bases1   = wsi + bases1_o;
    int* cursor1  = wsi + cursor1_o;
    int* bases2   = wsi + bases2_o;
    int* cursor2  = wsi + cursor2_o;
    ushort* tblu  = (ushort*)((char*)d_ws + tbl_off);
    ushort* tbli  = tblu + (size_t)n_users * DIM;
    uint2* pairs1 = (uint2*)((char*)d_ws + pairs1_off);
    uint2* pairs2 = (uint2*)((char*)d_ws + pairs2_off);

    to_bf16<<<2048, 256, 0, stream>>>(user_emb, n_users * DIM, tblu);
    to_bf16<<<2048, 256, 0, stream>>>(item_emb, n_items * DIM, tbli);

    const int p1_grid = (nnz + C1 - 1) / C1;

    // chunks-per-bucket: covers mean + >30 sigma of Binomial bucket sizes
    auto cpb_for = [&](int nrows_side) {
        const double mean = (double)nnz * (double)L1SZ / (double)nrows_side;
        const double cover = mean + 32.0 * __builtin_sqrt(mean) + 1024.0;
        int c = (int)((cover + C2 - 1) / (double)C2);
        return c < 1 ? 1 : c;
    };

    // -------- per-side pipeline: dest/nbr arrays, K1, table of OTHER side ----
    struct Side { const int* dest; const int* nbr; int nrows; int K1; int CPB;
                  const ushort* tbl; float* out; };
    const Side sides[2] = {
        { cols, rows, n_items, (n_items + L1SZ - 1) / L1SZ, cpb_for(n_items), tblu, item_out },
        { rows, cols, n_users, (n_users + L1SZ - 1) / L1SZ, cpb_for(n_users), tbli, user_out },
    };

    for (int s = 0; s < 2; ++s) {
        const Side& S = sides[s];
        const int K2 = S.K1 * SUBCNT;
        // zero counts1+counts2 (adjacent)
        hipMemsetAsync(counts1, 0, (K1MAX + K2MAX) * sizeof(int), stream);
        count1_kernel<<<1024, 256, 0, stream>>>(S.dest, nnz, S.K1, counts1);
        exscan_block<<<1, 1024, 0, stream>>>(counts1, S.K1, bases1, cursor1);
        p1_kernel<<<p1_grid, 256, 0, stream>>>(S.dest, S.nbr, vals, nnz, S.K1,
                                               cursor1, pairs1);
        const int g2 = S.K1 * S.CPB;
        count2_kernel<<<g2, 512, 0, stream>>>(pairs1, bases1, counts1, S.CPB, counts2);
        exscan_block<<<1, 1024, 0, stream>>>(counts2, K2, bases2, cursor2);
        p2_kernel<<<g2, 512, 0, stream>>>(pairs1, bases1, counts1, S.CPB,
                                          cursor2, pairs2);
        const int acc_grid = (S.nrows + 3) / 4;
        acc_kernel<<<acc_grid, 256, 0, stream>>>(S.tbl, pairs2, bases2, counts2,
                                                 S.nrows, S.out);
    }
}

// Round 10
// 1222.464 us; speedup vs baseline: 1.5153x; 1.5153x over previous
//
#include <hip/hip_runtime.h>

// LightGCN conv via exact 2-level counting sort + per-row register accumulate.
// Per side (sequential, shares buffers):
//   count1 -> exscan1 -> p1 (1024-row L1 buckets, 84/42-pair write runs)
//   count2 (per-chunk per-row counts, exclusive slices, no atomics)
//   scan2  (one block per bucket: exact per-(row,chunk) offsets + row_start)
//   p2     (LDS cursors from exact offsets, out-of-place scatter, SoA out)
//   acc    (one wave per output row, fully sorted pairs, unroll-8, bf16 gathers)
// R10: R9's acc filtered 4x redundantly (2x636us, VALUBusy 40%). Exact row
// sort restores R8's redundancy-free accumulate while keeping R9's
// long-run partition. SoA bf16 val keeps ws ~165MB (< proven ~180MB).

constexpr int DIM    = 64;
constexpr int L1BITS = 10;
constexpr int L1SZ   = 1 << L1BITS;       // rows per L1 bucket
constexpr int SHIFT  = 17;                // bits for neighbor id
constexpr unsigned NMASK = (1u << SHIFT) - 1;
constexpr int C1     = 8192;              // edges per p1 block
constexpr int CPB    = 8;                 // chunks per bucket (count2/p2)
constexpr int K1CAP  = 128;               // max L1 buckets per side

// ---------------- fallback (round-1) atomic kernel ----------------
__global__ void lightgcn_scatter_atomic(const float* __restrict__ user_emb,
                                        const float* __restrict__ item_emb,
                                        const int* __restrict__ rows,
                                        const int* __restrict__ cols,
                                        const float* __restrict__ vals,
                                        float* __restrict__ user_out,
                                        float* __restrict__ item_out,
                                        int nnz) {
    const int lane   = threadIdx.x & 63;
    const int wave   = (blockIdx.x * blockDim.x + threadIdx.x) >> 6;
    const int nwaves = (gridDim.x * blockDim.x) >> 6;
    for (int e = wave; e < nnz; e += nwaves) {
        const int r = rows[e];
        const int c = cols[e];
        const float v = vals[e];
        atomicAdd(&user_out[(size_t)r * DIM + lane], v * item_emb[(size_t)c * DIM + lane]);
        atomicAdd(&item_out[(size_t)c * DIM + lane], v * user_emb[(size_t)r * DIM + lane]);
    }
}

// ---------------- bf16 table conversion (RNE) ----------------
__global__ void to_bf16(const float* __restrict__ a, int n, ushort* __restrict__ o) {
    int i = blockIdx.x * blockDim.x + threadIdx.x;
    const int s = gridDim.x * blockDim.x;
    for (; i < n; i += s) {
        const unsigned u = __float_as_uint(a[i]);
        o[i] = (ushort)((u + 0x7FFFu + ((u >> 16) & 1u)) >> 16);
    }
}

// ---------------- count1: L1-bucket histogram (int4 loads) ----------------
__global__ __launch_bounds__(256)
void count1_kernel(const int* __restrict__ dest, int nnz, int K1,
                   int* __restrict__ counts1) {
    __shared__ int h[K1CAP * 4];
    const int tid = threadIdx.x;
    for (int t = tid; t < K1 * 4; t += 256) h[t] = 0;
    __syncthreads();
    const int rr = tid & 3;
    const int nq = nnz >> 2;
    const int4* d4 = (const int4*)dest;
    for (int i = blockIdx.x * 256 + tid; i < nq; i += gridDim.x * 256) {
        const int4 d = d4[i];
        atomicAdd(&h[((d.x >> L1BITS) << 2) | rr], 1);
        atomicAdd(&h[((d.y >> L1BITS) << 2) | rr], 1);
        atomicAdd(&h[((d.z >> L1BITS) << 2) | rr], 1);
        atomicAdd(&h[((d.w >> L1BITS) << 2) | rr], 1);
    }
    for (int i = (nq << 2) + blockIdx.x * 256 + tid; i < nnz; i += gridDim.x * 256)
        atomicAdd(&h[((dest[i] >> L1BITS) << 2) | rr], 1);
    __syncthreads();
    for (int b = tid; b < K1; b += 256) {
        const int c = h[b*4] + h[b*4+1] + h[b*4+2] + h[b*4+3];
        if (c) atomicAdd(&counts1[b], c);
    }
}

// ---------------- exscan over K1 buckets (1 block) ----------------
__global__ __launch_bounds__(1024)
void exscan_block(const int* __restrict__ src, int n,
                  int* __restrict__ base, int* __restrict__ cursor) {
    __shared__ int s[1024];
    const int tid = threadIdx.x;
    const int len = (n + 1023) >> 10;
    const int lo = min(tid * len, n);
    const int hi = min(lo + len, n);
    int sum = 0;
    for (int i = lo; i < hi; ++i) sum += src[i];
    s[tid] = sum;
    __syncthreads();
    for (int off = 1; off < 1024; off <<= 1) {
        const int t = (tid >= off) ? s[tid - off] : 0;
        __syncthreads();
        s[tid] += t;
        __syncthreads();
    }
    int run = tid ? s[tid - 1] : 0;
    for (int i = lo; i < hi; ++i) {
        const int c = src[i];
        base[i] = run; cursor[i] = run;
        run += c;
    }
}

// ---------------- p1: edges -> L1-bucket-grouped AoS pairs ----------------
__global__ __launch_bounds__(256)
void p1_kernel(const int* __restrict__ dest, const int* __restrict__ nbr,
               const float* __restrict__ vals, int nnz, int K1,
               int* __restrict__ cursor1, uint2* __restrict__ pairs1) {
    __shared__ int h[K1CAP * 4];
    __shared__ int gd[K1CAP];
    __shared__ int lc[K1CAP];
    const int tid = threadIdx.x;
    const int e0 = blockIdx.x * C1;
    const int e1 = min(e0 + C1, nnz);
    for (int t = tid; t < K1 * 4; t += 256) h[t] = 0;
    for (int t = tid; t < K1; t += 256) lc[t] = 0;
    __syncthreads();
    const int rr = tid & 3;
    const int nfull = (e1 - e0) & ~3;
    const int4* d4 = (const int4*)(dest + e0);
    for (int q = tid; q < (nfull >> 2); q += 256) {
        const int4 d = d4[q];
        atomicAdd(&h[((d.x >> L1BITS) << 2) | rr], 1);
        atomicAdd(&h[((d.y >> L1BITS) << 2) | rr], 1);
        atomicAdd(&h[((d.z >> L1BITS) << 2) | rr], 1);
        atomicAdd(&h[((d.w >> L1BITS) << 2) | rr], 1);
    }
    for (int e = e0 + nfull + tid; e < e1; e += 256)
        atomicAdd(&h[((dest[e] >> L1BITS) << 2) | rr], 1);
    __syncthreads();
    for (int b = tid; b < K1; b += 256) {
        const int c = h[b*4] + h[b*4+1] + h[b*4+2] + h[b*4+3];
        gd[b] = c ? atomicAdd(&cursor1[b], c) : 0;
    }
    __syncthreads();
    const int4*   n4 = (const int4*)(nbr + e0);
    const float4* v4 = (const float4*)(vals + e0);
    for (int q = tid; q < (nfull >> 2); q += 256) {
        const int4 d = d4[q];
        const int4 nb = n4[q];
        const float4 vv = v4[q];
        {   const int b = d.x >> L1BITS;
            const int s = gd[b] + atomicAdd(&lc[b], 1);
            pairs1[s] = make_uint2(((unsigned)(d.x & (L1SZ-1)) << SHIFT) | (unsigned)nb.x,
                                   __float_as_uint(vv.x)); }
        {   const int b = d.y >> L1BITS;
            const int s = gd[b] + atomicAdd(&lc[b], 1);
            pairs1[s] = make_uint2(((unsigned)(d.y & (L1SZ-1)) << SHIFT) | (unsigned)nb.y,
                                   __float_as_uint(vv.y)); }
        {   const int b = d.z >> L1BITS;
            const int s = gd[b] + atomicAdd(&lc[b], 1);
            pairs1[s] = make_uint2(((unsigned)(d.z & (L1SZ-1)) << SHIFT) | (unsigned)nb.z,
                                   __float_as_uint(vv.z)); }
        {   const int b = d.w >> L1BITS;
            const int s = gd[b] + atomicAdd(&lc[b], 1);
            pairs1[s] = make_uint2(((unsigned)(d.w & (L1SZ-1)) << SHIFT) | (unsigned)nb.w,
                                   __float_as_uint(vv.w)); }
    }
    for (int e = e0 + nfull + tid; e < e1; e += 256) {
        const int d = dest[e];
        const int b = d >> L1BITS;
        const int s = gd[b] + atomicAdd(&lc[b], 1);
        pairs1[s] = make_uint2(((unsigned)(d & (L1SZ-1)) << SHIFT) | (unsigned)nbr[e],
                               __float_as_uint(vals[e]));
    }
}

// ---------------- count2: per-(bucket,chunk) row histogram ----------------
// Block (B,j) owns counts2 slice [(B*CPB+j)*L1SZ, +L1SZ) exclusively: no
// global atomics; zeros written for empty chunks (scan2 reads everything).
__global__ __launch_bounds__(512)
void count2_kernel(const uint2* __restrict__ pairs1,
                   const int* __restrict__ bases1, const int* __restrict__ counts1,
                   int* __restrict__ counts2) {
    __shared__ int h[L1SZ * 4];   // 16 KiB
    const int B = blockIdx.x / CPB, j = blockIdx.x % CPB;
    const int n = counts1[B];
    const int csz = (n + CPB - 1) / CPB;
    const int s0 = bases1[B] + j * csz;
    const int s1 = min(s0 + csz, bases1[B] + n);
    const int tid = threadIdx.x;
    for (int t = tid; t < L1SZ * 4; t += 512) h[t] = 0;
    __syncthreads();
    const int rr = tid & 3;
    for (int i = s0 + tid; i < s1; i += 512) {
        const unsigned m = pairs1[i].x;
        atomicAdd(&h[((m >> SHIFT) << 2) | rr], 1);
    }
    __syncthreads();
    int* dstc = counts2 + (size_t)(B * CPB + j) * L1SZ;
    for (int r = tid; r < L1SZ; r += 512)
        dstc[r] = h[r*4] + h[r*4+1] + h[r*4+2] + h[r*4+3];
}

// ---------------- scan2: exact per-(row,chunk) offsets + row_start -----------
// One block per bucket. counts2 is converted IN PLACE to exclusive offsets in
// logical order (row-major, then chunk). row_start[B*L1SZ + r] = row r start.
__global__ __launch_bounds__(1024)
void scan2_kernel(const int* __restrict__ bases1, int K1,
                  int* __restrict__ counts2, int* __restrict__ row_start) {
    __shared__ int s[1024];
    const int B = blockIdx.x;
    const int tid = threadIdx.x;
    int rsum = 0;
    #pragma unroll
    for (int j = 0; j < CPB; ++j)
        rsum += counts2[(size_t)(B * CPB + j) * L1SZ + tid];
    s[tid] = rsum;
    __syncthreads();
    for (int off = 1; off < 1024; off <<= 1) {
        const int t = (tid >= off) ? s[tid - off] : 0;
        __syncthreads();
        s[tid] += t;
        __syncthreads();
    }
    int run = bases1[B] + (tid ? s[tid - 1] : 0);
    row_start[B * L1SZ + tid] = run;
    #pragma unroll
    for (int j = 0; j < CPB; ++j) {
        const size_t idx = (size_t)(B * CPB + j) * L1SZ + tid;
        const int c = counts2[idx];
        counts2[idx] = run;
        run += c;
    }
    if (B == K1 - 1 && tid == 1023) row_start[K1 * L1SZ] = run;   // == nnz
}

// ---------------- p2: scatter into exact slots (SoA out, bf16 val) -----------
__global__ __launch_bounds__(512)
void p2_kernel(const uint2* __restrict__ pairs1,
               const int* __restrict__ bases1, const int* __restrict__ counts1,
               const int* __restrict__ offsets2,
               unsigned* __restrict__ meta2, ushort* __restrict__ val2) {
    __shared__ int cur[L1SZ];
    const int B = blockIdx.x / CPB, j = blockIdx.x % CPB;
    const int n = counts1[B];
    const int csz = (n + CPB - 1) / CPB;
    const int s0 = bases1[B] + j * csz;
    const int s1 = min(s0 + csz, bases1[B] + n);
    const int tid = threadIdx.x;
    const int* src = offsets2 + (size_t)(B * CPB + j) * L1SZ;
    for (int r = tid; r < L1SZ; r += 512) cur[r] = src[r];
    __syncthreads();
    for (int i = s0 + tid; i < s1; i += 512) {
        const uint2 p = pairs1[i];
        const int row = (int)(p.x >> SHIFT);
        const int slot = atomicAdd(&cur[row], 1);
        meta2[slot] = p.x;
        const unsigned u = p.y;
        val2[slot] = (ushort)((u + 0x7FFFu + ((u >> 16) & 1u)) >> 16);
    }
}

// ---------------- acc: one wave per output row, sorted pairs, unroll-8 -------
__global__ __launch_bounds__(256)
void acc_kernel(const ushort* __restrict__ tbl,
                const unsigned* __restrict__ meta2,
                const ushort* __restrict__ val2,
                const int* __restrict__ row_start,
                int nrows, float* __restrict__ out) {
    const int lane = threadIdx.x & 63;
    const int r = (int)((blockIdx.x * blockDim.x + threadIdx.x) >> 6);
    const int st = row_start[r];
    const int en = row_start[r + 1];
    float acc = 0.f;
    int e = st;
    #define GB(m) __uint_as_float((unsigned)tbl[(size_t)((m) & NMASK) * DIM + lane] << 16)
    #define VB(x) __uint_as_float((unsigned)(x) << 16)
    for (; e + 8 <= en; e += 8) {
        const unsigned m0 = meta2[e+0], m1 = meta2[e+1], m2 = meta2[e+2], m3 = meta2[e+3];
        const unsigned m4 = meta2[e+4], m5 = meta2[e+5], m6 = meta2[e+6], m7 = meta2[e+7];
        const float v0 = VB(val2[e+0]), v1 = VB(val2[e+1]), v2 = VB(val2[e+2]), v3 = VB(val2[e+3]);
        const float v4 = VB(val2[e+4]), v5 = VB(val2[e+5]), v6 = VB(val2[e+6]), v7 = VB(val2[e+7]);
        const float g0 = GB(m0), g1 = GB(m1), g2 = GB(m2), g3 = GB(m3);
        const float g4 = GB(m4), g5 = GB(m5), g6 = GB(m6), g7 = GB(m7);
        acc = fmaf(v0, g0, acc); acc = fmaf(v1, g1, acc);
        acc = fmaf(v2, g2, acc); acc = fmaf(v3, g3, acc);
        acc = fmaf(v4, g4, acc); acc = fmaf(v5, g5, acc);
        acc = fmaf(v6, g6, acc); acc = fmaf(v7, g7, acc);
    }
    for (; e < en; ++e)
        acc = fmaf(VB(val2[e]), GB(meta2[e]), acc);
    #undef GB
    #undef VB
    if (r < nrows) out[(size_t)r * DIM + lane] = acc;
}

extern "C" void kernel_launch(void* const* d_in, const int* in_sizes, int n_in,
                              void* d_out, int out_size, void* d_ws, size_t ws_size,
                              hipStream_t stream) {
    const float* user_emb = (const float*)d_in[0];
    const float* item_emb = (const float*)d_in[1];
    const int*   rows     = (const int*)d_in[2];
    const int*   cols     = (const int*)d_in[3];
    const float* vals     = (const float*)d_in[4];

    const int nnz     = in_sizes[2];
    const int n_users = in_sizes[0] / DIM;
    const int n_items = in_sizes[1] / DIM;

    float* user_out = (float*)d_out;
    float* item_out = (float*)d_out + (size_t)in_sizes[0];

    // ---- workspace layout ----
    size_t oi = 0;
    const size_t counts1_o  = oi; oi += K1CAP;
    const size_t bases1_o   = oi; oi += K1CAP;
    const size_t cursor1_o  = oi; oi += K1CAP;
    const size_t counts2_o  = oi; oi += (size_t)K1CAP * CPB * L1SZ;   // 1.05M ints
    const size_t rowstart_o = oi; oi += (size_t)K1CAP * L1SZ + 64;
    const size_t meta_bytes = oi * sizeof(int);
    const size_t tbl_off     = (meta_bytes + 255) & ~(size_t)255;
    const size_t tblu_bytes  = (size_t)n_users * DIM * sizeof(ushort);
    const size_t tbli_bytes  = (size_t)n_items * DIM * sizeof(ushort);
    const size_t pairs1_off  = (tbl_off + tblu_bytes + tbli_bytes + 255) & ~(size_t)255;
    const size_t pairs1_bytes = (size_t)nnz * sizeof(uint2);
    const size_t meta2_off   = pairs1_off + ((pairs1_bytes + 255) & ~(size_t)255);
    const size_t meta2_bytes = (size_t)nnz * sizeof(unsigned);
    const size_t val2_off    = meta2_off + ((meta2_bytes + 255) & ~(size_t)255);
    const size_t need        = val2_off + (size_t)nnz * sizeof(ushort);

    if (n_users > (1 << SHIFT) || n_items > (1 << SHIFT) ||
        n_users > K1CAP * L1SZ || n_items > K1CAP * L1SZ || ws_size < need) {
        hipMemsetAsync(d_out, 0, (size_t)out_size * sizeof(float), stream);
        lightgcn_scatter_atomic<<<2048, 256, 0, stream>>>(user_emb, item_emb, rows,
                                                          cols, vals, user_out,
                                                          item_out, nnz);
        return;
    }

    int* wsi       = (int*)d_ws;
    int* counts1   = wsi + counts1_o;
    int* bases1    = wsi + bases1_o;
    int* cursor1   = wsi + cursor1_o;
    int* counts2   = wsi + counts2_o;
    int* row_start = wsi + rowstart_o;
    ushort* tblu   = (ushort*)((char*)d_ws + tbl_off);
    ushort* tbli   = tblu + (size_t)n_users * DIM;
    uint2*    pairs1 = (uint2*)((char*)d_ws + pairs1_off);
    unsigned* meta2  = (unsigned*)((char*)d_ws + meta2_off);
    ushort*   val2   = (ushort*)((char*)d_ws + val2_off);

    to_bf16<<<2048, 256, 0, stream>>>(user_emb, n_users * DIM, tblu);
    to_bf16<<<2048, 256, 0, stream>>>(item_emb, n_items * DIM, tbli);

    const int p1_grid = (nnz + C1 - 1) / C1;

    struct Side { const int* dest; const int* nbr; int nrows; const ushort* tbl; float* out; };
    const Side sides[2] = {
        { cols, rows, n_items, tblu, item_out },   // item side gathers USER rows
        { rows, cols, n_users, tbli, user_out },   // user side gathers ITEM rows
    };

    for (int s = 0; s < 2; ++s) {
        const Side& S = sides[s];
        const int K1 = (S.nrows + L1SZ - 1) >> L1BITS;
        hipMemsetAsync(counts1, 0, (size_t)K1 * sizeof(int), stream);
        count1_kernel<<<1024, 256, 0, stream>>>(S.dest, nnz, K1, counts1);
        exscan_block<<<1, 1024, 0, stream>>>(counts1, K1, bases1, cursor1);
        p1_kernel<<<p1_grid, 256, 0, stream>>>(S.dest, S.nbr, vals, nnz, K1,
                                               cursor1, pairs1);
        count2_kernel<<<K1 * CPB, 512, 0, stream>>>(pairs1, bases1, counts1, counts2);
        scan2_kernel<<<K1, 1024, 0, stream>>>(bases1, K1, counts2, row_start);
        p2_kernel<<<K1 * CPB, 512, 0, stream>>>(pairs1, bases1, counts1, counts2,
                                                meta2, val2);
        const int acc_grid = K1 * L1SZ / 4;   // 4 rows (waves) per block
        acc_kernel<<<acc_grid, 256, 0, stream>>>(S.tbl, meta2, val2, row_start,
                                                 S.nrows, S.out);
    }
}

// Round 11
// 1092.051 us; speedup vs baseline: 1.6962x; 1.1194x over previous
//
#include <hip/hip_runtime.h>

// LightGCN conv via exact 2-level counting sort + per-row register accumulate.
// Per side (sequential, shares buffers):
//   count1 -> exscan1 -> p1 (1024-row L1 buckets, SoA meta/bf16-val out)
//   count2 (per-chunk per-row counts, exclusive slices, no atomics)
//   scan2  (one block per bucket: exact per-(row,chunk) offsets + row_start)
//   p2     (LDS cursors from exact offsets, out-of-place scatter)
//   acc    (one wave per row; 2 dims/lane so one gather serves 2 edges,
//           halving VMEM ops; cross-half merge via shfl_xor(32))
// R11: R10's acc (2x254us) does 3 VMEM ops/edge at 45% VALU / 25% HBM ->
// VMEM-issue bound hypothesis. Also SoA bf16 vals cut sort traffic ~160MB.

constexpr int DIM    = 64;
constexpr int L1BITS = 10;
constexpr int L1SZ   = 1 << L1BITS;       // rows per L1 bucket
constexpr int SHIFT  = 17;                // bits for neighbor id
constexpr unsigned NMASK = (1u << SHIFT) - 1;
constexpr int C1     = 8192;              // edges per p1 block
constexpr int CPB    = 8;                 // chunks per bucket (count2/p2)
constexpr int K1CAP  = 128;               // max L1 buckets per side

__device__ __forceinline__ ushort f2bf(unsigned u) {
    return (ushort)((u + 0x7FFFu + ((u >> 16) & 1u)) >> 16);
}
__device__ __forceinline__ float bf2f(ushort b) {
    return __uint_as_float((unsigned)b << 16);
}

// ---------------- fallback (round-1) atomic kernel ----------------
__global__ void lightgcn_scatter_atomic(const float* __restrict__ user_emb,
                                        const float* __restrict__ item_emb,
                                        const int* __restrict__ rows,
                                        const int* __restrict__ cols,
                                        const float* __restrict__ vals,
                                        float* __restrict__ user_out,
                                        float* __restrict__ item_out,
                                        int nnz) {
    const int lane   = threadIdx.x & 63;
    const int wave   = (blockIdx.x * blockDim.x + threadIdx.x) >> 6;
    const int nwaves = (gridDim.x * blockDim.x) >> 6;
    for (int e = wave; e < nnz; e += nwaves) {
        const int r = rows[e];
        const int c = cols[e];
        const float v = vals[e];
        atomicAdd(&user_out[(size_t)r * DIM + lane], v * item_emb[(size_t)c * DIM + lane]);
        atomicAdd(&item_out[(size_t)c * DIM + lane], v * user_emb[(size_t)r * DIM + lane]);
    }
}

// ---------------- bf16 table conversion (RNE) ----------------
__global__ void to_bf16(const float* __restrict__ a, int n, ushort* __restrict__ o) {
    int i = blockIdx.x * blockDim.x + threadIdx.x;
    const int s = gridDim.x * blockDim.x;
    for (; i < n; i += s) o[i] = f2bf(__float_as_uint(a[i]));
}

// ---------------- count1: L1-bucket histogram (int4 loads) ----------------
__global__ __launch_bounds__(256)
void count1_kernel(const int* __restrict__ dest, int nnz, int K1,
                   int* __restrict__ counts1) {
    __shared__ int h[K1CAP * 4];
    const int tid = threadIdx.x;
    for (int t = tid; t < K1 * 4; t += 256) h[t] = 0;
    __syncthreads();
    const int rr = tid & 3;
    const int nq = nnz >> 2;
    const int4* d4 = (const int4*)dest;
    for (int i = blockIdx.x * 256 + tid; i < nq; i += gridDim.x * 256) {
        const int4 d = d4[i];
        atomicAdd(&h[((d.x >> L1BITS) << 2) | rr], 1);
        atomicAdd(&h[((d.y >> L1BITS) << 2) | rr], 1);
        atomicAdd(&h[((d.z >> L1BITS) << 2) | rr], 1);
        atomicAdd(&h[((d.w >> L1BITS) << 2) | rr], 1);
    }
    for (int i = (nq << 2) + blockIdx.x * 256 + tid; i < nnz; i += gridDim.x * 256)
        atomicAdd(&h[((dest[i] >> L1BITS) << 2) | rr], 1);
    __syncthreads();
    for (int b = tid; b < K1; b += 256) {
        const int c = h[b*4] + h[b*4+1] + h[b*4+2] + h[b*4+3];
        if (c) atomicAdd(&counts1[b], c);
    }
}

// ---------------- exscan over K1 buckets (1 block) ----------------
__global__ __launch_bounds__(1024)
void exscan_block(const int* __restrict__ src, int n,
                  int* __restrict__ base, int* __restrict__ cursor) {
    __shared__ int s[1024];
    const int tid = threadIdx.x;
    const int len = (n + 1023) >> 10;
    const int lo = min(tid * len, n);
    const int hi = min(lo + len, n);
    int sum = 0;
    for (int i = lo; i < hi; ++i) sum += src[i];
    s[tid] = sum;
    __syncthreads();
    for (int off = 1; off < 1024; off <<= 1) {
        const int t = (tid >= off) ? s[tid - off] : 0;
        __syncthreads();
        s[tid] += t;
        __syncthreads();
    }
    int run = tid ? s[tid - 1] : 0;
    for (int i = lo; i < hi; ++i) {
        const int c = src[i];
        base[i] = run; cursor[i] = run;
        run += c;
    }
}

// ---------------- p1: edges -> L1-bucket-grouped SoA (meta, bf16 val) --------
__global__ __launch_bounds__(256)
void p1_kernel(const int* __restrict__ dest, const int* __restrict__ nbr,
               const float* __restrict__ vals, int nnz, int K1,
               int* __restrict__ cursor1,
               unsigned* __restrict__ meta1, ushort* __restrict__ val1) {
    __shared__ int h[K1CAP * 4];
    __shared__ int gd[K1CAP];
    __shared__ int lc[K1CAP];
    const int tid = threadIdx.x;
    const int e0 = blockIdx.x * C1;
    const int e1 = min(e0 + C1, nnz);
    for (int t = tid; t < K1 * 4; t += 256) h[t] = 0;
    for (int t = tid; t < K1; t += 256) lc[t] = 0;
    __syncthreads();
    const int rr = tid & 3;
    const int nfull = (e1 - e0) & ~3;
    const int4* d4 = (const int4*)(dest + e0);
    for (int q = tid; q < (nfull >> 2); q += 256) {
        const int4 d = d4[q];
        atomicAdd(&h[((d.x >> L1BITS) << 2) | rr], 1);
        atomicAdd(&h[((d.y >> L1BITS) << 2) | rr], 1);
        atomicAdd(&h[((d.z >> L1BITS) << 2) | rr], 1);
        atomicAdd(&h[((d.w >> L1BITS) << 2) | rr], 1);
    }
    for (int e = e0 + nfull + tid; e < e1; e += 256)
        atomicAdd(&h[((dest[e] >> L1BITS) << 2) | rr], 1);
    __syncthreads();
    for (int b = tid; b < K1; b += 256) {
        const int c = h[b*4] + h[b*4+1] + h[b*4+2] + h[b*4+3];
        gd[b] = c ? atomicAdd(&cursor1[b], c) : 0;
    }
    __syncthreads();
    const int4*   n4 = (const int4*)(nbr + e0);
    const float4* v4 = (const float4*)(vals + e0);
    for (int q = tid; q < (nfull >> 2); q += 256) {
        const int4 d = d4[q];
        const int4 nb = n4[q];
        const float4 vv = v4[q];
        {   const int b = d.x >> L1BITS;
            const int s = gd[b] + atomicAdd(&lc[b], 1);
            meta1[s] = ((unsigned)(d.x & (L1SZ-1)) << SHIFT) | (unsigned)nb.x;
            val1[s] = f2bf(__float_as_uint(vv.x)); }
        {   const int b = d.y >> L1BITS;
            const int s = gd[b] + atomicAdd(&lc[b], 1);
            meta1[s] = ((unsigned)(d.y & (L1SZ-1)) << SHIFT) | (unsigned)nb.y;
            val1[s] = f2bf(__float_as_uint(vv.y)); }
        {   const int b = d.z >> L1BITS;
            const int s = gd[b] + atomicAdd(&lc[b], 1);
            meta1[s] = ((unsigned)(d.z & (L1SZ-1)) << SHIFT) | (unsigned)nb.z;
            val1[s] = f2bf(__float_as_uint(vv.z)); }
        {   const int b = d.w >> L1BITS;
            const int s = gd[b] + atomicAdd(&lc[b], 1);
            meta1[s] = ((unsigned)(d.w & (L1SZ-1)) << SHIFT) | (unsigned)nb.w;
            val1[s] = f2bf(__float_as_uint(vv.w)); }
    }
    for (int e = e0 + nfull + tid; e < e1; e += 256) {
        const int d = dest[e];
        const int b = d >> L1BITS;
        const int s = gd[b] + atomicAdd(&lc[b], 1);
        meta1[s] = ((unsigned)(d & (L1SZ-1)) << SHIFT) | (unsigned)nbr[e];
        val1[s] = f2bf(__float_as_uint(vals[e]));
    }
}

// ---------------- count2: per-(bucket,chunk) row histogram ----------------
__global__ __launch_bounds__(512)
void count2_kernel(const unsigned* __restrict__ meta1,
                   const int* __restrict__ bases1, const int* __restrict__ counts1,
                   int* __restrict__ counts2) {
    __shared__ int h[L1SZ * 4];   // 16 KiB
    const int B = blockIdx.x / CPB, j = blockIdx.x % CPB;
    const int n = counts1[B];
    const int csz = (n + CPB - 1) / CPB;
    const int s0 = bases1[B] + j * csz;
    const int s1 = min(s0 + csz, bases1[B] + n);
    const int tid = threadIdx.x;
    for (int t = tid; t < L1SZ * 4; t += 512) h[t] = 0;
    __syncthreads();
    const int rr = tid & 3;
    for (int i = s0 + tid; i < s1; i += 512)
        atomicAdd(&h[((meta1[i] >> SHIFT) << 2) | rr], 1);
    __syncthreads();
    int* dstc = counts2 + (size_t)(B * CPB + j) * L1SZ;
    for (int r = tid; r < L1SZ; r += 512)
        dstc[r] = h[r*4] + h[r*4+1] + h[r*4+2] + h[r*4+3];
}

// ---------------- scan2: exact per-(row,chunk) offsets + row_start -----------
__global__ __launch_bounds__(1024)
void scan2_kernel(const int* __restrict__ bases1, int K1,
                  int* __restrict__ counts2, int* __restrict__ row_start) {
    __shared__ int s[1024];
    const int B = blockIdx.x;
    const int tid = threadIdx.x;
    int rsum = 0;
    #pragma unroll
    for (int j = 0; j < CPB; ++j)
        rsum += counts2[(size_t)(B * CPB + j) * L1SZ + tid];
    s[tid] = rsum;
    __syncthreads();
    for (int off = 1; off < 1024; off <<= 1) {
        const int t = (tid >= off) ? s[tid - off] : 0;
        __syncthreads();
        s[tid] += t;
        __syncthreads();
    }
    int run = bases1[B] + (tid ? s[tid - 1] : 0);
    row_start[B * L1SZ + tid] = run;
    #pragma unroll
    for (int j = 0; j < CPB; ++j) {
        const size_t idx = (size_t)(B * CPB + j) * L1SZ + tid;
        const int c = counts2[idx];
        counts2[idx] = run;
        run += c;
    }
    if (B == K1 - 1 && tid == 1023) row_start[K1 * L1SZ] = run;   // == nnz
}

// ---------------- p2: scatter into exact slots (SoA in and out) --------------
__global__ __launch_bounds__(512)
void p2_kernel(const unsigned* __restrict__ meta1, const ushort* __restrict__ val1,
               const int* __restrict__ bases1, const int* __restrict__ counts1,
               const int* __restrict__ offsets2,
               unsigned* __restrict__ meta2, ushort* __restrict__ val2) {
    __shared__ int cur[L1SZ];
    const int B = blockIdx.x / CPB, j = blockIdx.x % CPB;
    const int n = counts1[B];
    const int csz = (n + CPB - 1) / CPB;
    const int s0 = bases1[B] + j * csz;
    const int s1 = min(s0 + csz, bases1[B] + n);
    const int tid = threadIdx.x;
    const int* src = offsets2 + (size_t)(B * CPB + j) * L1SZ;
    for (int r = tid; r < L1SZ; r += 512) cur[r] = src[r];
    __syncthreads();
    for (int i = s0 + tid; i < s1; i += 512) {
        const unsigned m = meta1[i];
        const int slot = atomicAdd(&cur[m >> SHIFT], 1);
        meta2[slot] = m;
        val2[slot] = val1[i];
    }
}

// ---------------- acc: one wave per row; 2 dims/lane, 2 edges/instruction ----
// Lane half h = lane>>5 handles edges e+h; each lane gathers ushort2 (dims
// 2*li, 2*li+1) so one VMEM instruction serves 2 edges. Cross-half merge via
// shfl_xor(32); halves 0 stores float2 (coalesced 256B per row).
__global__ __launch_bounds__(256)
void acc_kernel(const ushort* __restrict__ tbl,
                const unsigned* __restrict__ meta2,
                const ushort* __restrict__ val2,
                const int* __restrict__ row_start,
                int nrows, float* __restrict__ out) {
    const int lane = threadIdx.x & 63;
    const int half = lane >> 5;
    const int li   = lane & 31;
    const int r = (int)((blockIdx.x * blockDim.x + threadIdx.x) >> 6);
    const int st = row_start[r];
    const int en = row_start[r + 1];
    float ax = 0.f, ay = 0.f;
    int e = st;
    #define STEP(EI) {                                                        \
        const unsigned m_ = meta2[EI];                                        \
        const float v_ = bf2f(val2[EI]);                                      \
        const ushort2 g_ = *(const ushort2*)(tbl + (size_t)(m_ & NMASK) * DIM + 2*li); \
        ax = fmaf(v_, bf2f(g_.x), ax);                                        \
        ay = fmaf(v_, bf2f(g_.y), ay); }
    for (; e + 8 <= en; e += 8) {
        STEP(e + 0 + half); STEP(e + 2 + half);
        STEP(e + 4 + half); STEP(e + 6 + half);
    }
    for (; e + 2 <= en; e += 2) STEP(e + half);
    if (e < en && half == 0) STEP(e);
    #undef STEP
    ax += __shfl_xor(ax, 32);
    ay += __shfl_xor(ay, 32);
    if (half == 0 && r < nrows)
        *(float2*)(out + (size_t)r * DIM + 2*li) = make_float2(ax, ay);
}

extern "C" void kernel_launch(void* const* d_in, const int* in_sizes, int n_in,
                              void* d_out, int out_size, void* d_ws, size_t ws_size,
                              hipStream_t stream) {
    const float* user_emb = (const float*)d_in[0];
    const float* item_emb = (const float*)d_in[1];
    const int*   rows     = (const int*)d_in[2];
    const int*   cols     = (const int*)d_in[3];
    const float* vals     = (const float*)d_in[4];

    const int nnz     = in_sizes[2];
    const int n_users = in_sizes[0] / DIM;
    const int n_items = in_sizes[1] / DIM;

    float* user_out = (float*)d_out;
    float* item_out = (float*)d_out + (size_t)in_sizes[0];

    // ---- workspace layout ----
    size_t oi = 0;
    const size_t counts1_o  = oi; oi += K1CAP;
    const size_t bases1_o   = oi; oi += K1CAP;
    const size_t cursor1_o  = oi; oi += K1CAP;
    const size_t counts2_o  = oi; oi += (size_t)K1CAP * CPB * L1SZ;
    const size_t rowstart_o = oi; oi += (size_t)K1CAP * L1SZ + 64;
    const size_t meta_bytes = oi * sizeof(int);
    const size_t tbl_off     = (meta_bytes + 255) & ~(size_t)255;
    const size_t tblu_bytes  = (size_t)n_users * DIM * sizeof(ushort);
    const size_t tbli_bytes  = (size_t)n_items * DIM * sizeof(ushort);
    const size_t meta1_off   = (tbl_off + tblu_bytes + tbli_bytes + 255) & ~(size_t)255;
    const size_t val1_off    = meta1_off + (((size_t)nnz * 4 + 255) & ~(size_t)255);
    const size_t meta2_off   = val1_off + (((size_t)nnz * 2 + 255) & ~(size_t)255);
    const size_t val2_off    = meta2_off + (((size_t)nnz * 4 + 255) & ~(size_t)255);
    const size_t need        = val2_off + (size_t)nnz * sizeof(ushort);

    if (n_users > (1 << SHIFT) || n_items > (1 << SHIFT) ||
        n_users > K1CAP * L1SZ || n_items > K1CAP * L1SZ || ws_size < need) {
        hipMemsetAsync(d_out, 0, (size_t)out_size * sizeof(float), stream);
        lightgcn_scatter_atomic<<<2048, 256, 0, stream>>>(user_emb, item_emb, rows,
                                                          cols, vals, user_out,
                                                          item_out, nnz);
        return;
    }

    int* wsi       = (int*)d_ws;
    int* counts1   = wsi + counts1_o;
    int* bases1    = wsi + bases1_o;
    int* cursor1   = wsi + cursor1_o;
    int* counts2   = wsi + counts2_o;
    int* row_start = wsi + rowstart_o;
    ushort* tblu   = (ushort*)((char*)d_ws + tbl_off);
    ushort* tbli   = tblu + (size_t)n_users * DIM;
    unsigned* meta1 = (unsigned*)((char*)d_ws + meta1_off);
    ushort*   val1  = (ushort*)((char*)d_ws + val1_off);
    unsigned* meta2 = (unsigned*)((char*)d_ws + meta2_off);
    ushort*   val2  = (ushort*)((char*)d_ws + val2_off);

    to_bf16<<<2048, 256, 0, stream>>>(user_emb, n_users * DIM, tblu);
    to_bf16<<<2048, 256, 0, stream>>>(item_emb, n_items * DIM, tbli);

    const int p1_grid = (nnz + C1 - 1) / C1;

    struct Side { const int* dest; const int* nbr; int nrows; const ushort* tbl; float* out; };
    const Side sides[2] = {
        { cols, rows, n_items, tblu, item_out },   // item side gathers USER rows
        { rows, cols, n_users, tbli, user_out },   // user side gathers ITEM rows
    };

    for (int s = 0; s < 2; ++s) {
        const Side& S = sides[s];
        const int K1 = (S.nrows + L1SZ - 1) >> L1BITS;
        hipMemsetAsync(counts1, 0, (size_t)K1 * sizeof(int), stream);
        count1_kernel<<<1024, 256, 0, stream>>>(S.dest, nnz, K1, counts1);
        exscan_block<<<1, 1024, 0, stream>>>(counts1, K1, bases1, cursor1);
        p1_kernel<<<p1_grid, 256, 0, stream>>>(S.dest, S.nbr, vals, nnz, K1,
                                               cursor1, meta1, val1);
        count2_kernel<<<K1 * CPB, 512, 0, stream>>>(meta1, bases1, counts1, counts2);
        scan2_kernel<<<K1, 1024, 0, stream>>>(bases1, K1, counts2, row_start);
        p2_kernel<<<K1 * CPB, 512, 0, stream>>>(meta1, val1, bases1, counts1,
                                                counts2, meta2, val2);
        const int acc_grid = K1 * L1SZ / 4;   // 4 rows (waves) per block
        acc_kernel<<<acc_grid, 256, 0, stream>>>(S.tbl, meta2, val2, row_start,
                                                 S.nrows, S.out);
    }
}